// Round 10
// baseline (2929.862 us; speedup 1.0000x reference)
//
#include <hip/hip_runtime.h>
#include <hip/hip_bf16.h>
#include <math.h>

#define BB 8
#define NN 4096
#define NS 1024
#define CC 64
#define OO 128
#define MM 16
#define GAMMA_C 16.0f
#define INV_TAU 1.0f
#define KK 32
#define NP_ELEMS (BB*NS*3)

// ---- workspace layout (units: 4-byte elements) ----
#define WS_LFA   0                           // float[B*O*NS]
#define WS_LFB   (WS_LFA + BB*OO*NS)         // float[B*O*NS]
#define WS_GO    (WS_LFB + BB*OO*NS)         // float[B*O*NS]
#define WS_H     (WS_GO + BB*OO*NS)          // float[B*NS*384]
#define WS_FI    (WS_H + BB*NS*384)          // float[B*C*NS]
#define WS_IDX   (WS_FI + BB*CC*NS)          // int[B*NS]
#define WS_GIDXA (WS_IDX + BB*NS)            // int[B*NS*K]
#define WS_GIDXB (WS_GIDXA + BB*NS*KK)       // int[B*NS*K]
#define WS_FLAG  (WS_GIDXB + BB*NS*KK)       // int[B*NS]
#define WS_PROBS (WS_FLAG + BB*NS)           // float[B*M*NS]
#define WS_GP    (WS_PROBS + BB*MM*NS)       // float[B*M*3]
#define WS_GF    (WS_GP + BB*MM*3)           // float[B*C*M]

__device__ inline float wave_max_f(float v) {
#pragma unroll
    for (int o = 32; o; o >>= 1) v = fmaxf(v, __shfl_xor(v, o, 64));
    return v;
}
__device__ inline float wave_sum_f(float v) {
#pragma unroll
    for (int o = 32; o; o >>= 1) v += __shfl_xor(v, o, 64);
    return v;
}

// packed (distbits, ~idx) compare: strict total order (idx unique); u64-max
// tie-breaks to SMALLEST index = numpy argmax first-occurrence. Carries the
// winning point's coordinates (pure data movement, no arithmetic change).
__device__ inline void cmax5(unsigned& bh, unsigned& bl, float& bx, float& by, float& bz,
                             unsigned ch, unsigned cl, float cx, float cy, float cz) {
    if (ch > bh || (ch == bh && cl > bl)) { bh = ch; bl = cl; bx = cx; by = cy; bz = cz; }
}
template<int CTRL>
__device__ inline void dpp5_max(unsigned& bh, unsigned& bl, float& bx, float& by, float& bz) {
    const unsigned nh = (unsigned)__builtin_amdgcn_mov_dpp((int)bh, CTRL, 0xF, 0xF, true);
    const unsigned nl = (unsigned)__builtin_amdgcn_mov_dpp((int)bl, CTRL, 0xF, 0xF, true);
    const float nx = __int_as_float(__builtin_amdgcn_mov_dpp(__float_as_int(bx), CTRL, 0xF, 0xF, true));
    const float ny = __int_as_float(__builtin_amdgcn_mov_dpp(__float_as_int(by), CTRL, 0xF, 0xF, true));
    const float nz = __int_as_float(__builtin_amdgcn_mov_dpp(__float_as_int(bz), CTRL, 0xF, 0xF, true));
    cmax5(bh, bl, bx, by, bz, nh, nl, nx, ny, nz);
}
#define ROR1  0x121
#define ROR2  0x122
#define ROR4  0x124
#define ROR8  0x128
#define BC15  0x142
#define BC31  0x143

// ---------------- 1. Farthest point sampling ----------------
// 512 threads (8 waves, 2/SIMD), 8 points/thread in registers. The winner's
// coordinates ride the reduction (no serial px[last] LDS read). Tree combine
// (depth 3) + 6 DPP wave steps + 1 barrier + 3 DPP cross-wave steps per
// iteration. Distances: literal-order f32, contract off — bit-identical to
// the numpy reference; total-order packed max makes the result independent
// of partition/reduction topology.
__global__ __launch_bounds__(512) void k_fps(const float* __restrict__ p,
                                             int* __restrict__ idx_out,
                                             float* __restrict__ newp)
{
#pragma clang fp contract(off)
    const int b    = blockIdx.x;
    const int tid  = threadIdx.x;
    const int lane = tid & 63;
    const int wave = tid >> 6;     // 0..7
    __shared__ float px[NN], py[NN], pz[NN];
    __shared__ unsigned phi[2][8], plo[2][8];
    __shared__ float pwx[2][8], pwy[2][8], pwz[2][8];
    __shared__ int sidx[NS];
    const float* pb = p + (size_t)b*NN*3;
    float pxr[8], pyr[8], pzr[8], dd[8];
#pragma unroll
    for (int q = 0; q < 8; ++q) {
        const int j = tid + q*512;
        const float x = pb[j*3+0], y = pb[j*3+1], z = pb[j*3+2];
        px[j] = x; py[j] = y; pz[j] = z;
        pxr[q] = x; pyr[q] = y; pzr[q] = z;
        dd[q] = 1e10f;
    }
    if (tid == 0) sidx[0] = 0;
    __syncthreads();
    float lx = px[0], ly = py[0], lz = pz[0];
    for (int it = 1; it < NS; ++it) {
        unsigned hh[8], ll[8];
        float cx[8], cy[8], cz[8];
#pragma unroll
        for (int q = 0; q < 8; ++q) {
            const float dx = pxr[q]-lx, dy = pyr[q]-ly, dz = pzr[q]-lz;
            const float d = dx*dx + dy*dy + dz*dz;
            dd[q] = fminf(dd[q], d);
            hh[q] = __float_as_uint(dd[q]);
            ll[q] = ~(unsigned)(tid + q*512);
            cx[q] = pxr[q]; cy[q] = pyr[q]; cz[q] = pzr[q];
        }
        // tree combine: depth 3
#pragma unroll
        for (int st = 1; st < 8; st <<= 1)
#pragma unroll
            for (int q = 0; q < 8; q += 2*st)
                cmax5(hh[q], ll[q], cx[q], cy[q], cz[q],
                      hh[q+st], ll[q+st], cx[q+st], cy[q+st], cz[q+st]);
        unsigned bh = hh[0], bl = ll[0];
        float bx = cx[0], by = cy[0], bz = cz[0];
        // wave reduce
        dpp5_max<ROR1>(bh, bl, bx, by, bz);
        dpp5_max<ROR2>(bh, bl, bx, by, bz);
        dpp5_max<ROR4>(bh, bl, bx, by, bz);
        dpp5_max<ROR8>(bh, bl, bx, by, bz);
        dpp5_max<BC15>(bh, bl, bx, by, bz);
        dpp5_max<BC31>(bh, bl, bx, by, bz);  // lane 63 holds wave winner
        const int buf = it & 1;
        if (lane == 63) {
            phi[buf][wave] = bh; plo[buf][wave] = bl;
            pwx[buf][wave] = bx; pwy[buf][wave] = by; pwz[buf][wave] = bz;
        }
        __syncthreads();
        // all waves redundantly reduce the 8 partials (period-8 in 16-row:
        // ROR1+ROR2+ROR4 covers all 8 residues)
        unsigned h2 = phi[buf][lane & 7], l2 = plo[buf][lane & 7];
        float x2 = pwx[buf][lane & 7], y2 = pwy[buf][lane & 7], z2 = pwz[buf][lane & 7];
        dpp5_max<ROR1>(h2, l2, x2, y2, z2);
        dpp5_max<ROR2>(h2, l2, x2, y2, z2);
        dpp5_max<ROR4>(h2, l2, x2, y2, z2);
        lx = x2; ly = y2; lz = z2;           // next center, straight from regs
        if (tid == 0) sidx[it] = (int)(~l2);
    }
    __syncthreads();
    for (int s = tid; s < NS; s += 512) {
        const int j = sidx[s];
        idx_out[b*NS + s] = j;
        newp[((size_t)b*NS + s)*3 + 0] = px[j];
        newp[((size_t)b*NS + s)*3 + 1] = py[j];
        newp[((size_t)b*NS + s)*3 + 2] = pz[j];
    }
}

// ---------------- 2. gather fi ----------------
__global__ __launch_bounds__(256) void k_gather_fi(const float* __restrict__ f,
                                                   const int* __restrict__ idx,
                                                   float* __restrict__ fi)
{
    const int bc = blockIdx.x;
    const int b  = bc >> 6;
    const float* frow = f + (size_t)bc * NN;
    float* firow = fi + (size_t)bc * NS;
    const int* ib = idx + b*NS;
    for (int s = threadIdx.x; s < NS; s += 256) firow[s] = frow[ib[s]];
}

// ---------------- 3. ball query with marginal-pair dual sets ----------------
__global__ __launch_bounds__(256) void k_ball2(const float* __restrict__ p,
                                               const float* __restrict__ newp,
                                               int* __restrict__ gA, int* __restrict__ gB,
                                               int* __restrict__ flag)
{
    const int b    = blockIdx.y;
    const int wave = threadIdx.x >> 6;
    const int lane = threadIdx.x & 63;
    const int s    = blockIdx.x * 4 + wave;
    __shared__ int sA[4][KK], sB[4][KK];
    const float* pb = p + (size_t)b*NN*3;
    const double sx = (double)newp[((size_t)b*NS+s)*3+0];
    const double sy = (double)newp[((size_t)b*NS+s)*3+1];
    const double sz = (double)newp[((size_t)b*NS+s)*3+2];
    const double ns2 = sx*sx + sy*sy + sz*sz;
    const double R2D = (double)(0.0225f);
    const double EPSD = 1.5e-7;
    int cntA = 0, cntB = 0, firstA = 0, firstB = 0;
    for (int base = 0; base < NN; base += 64) {
        const int j = base + lane;
        const double x = (double)pb[j*3+0];
        const double y = (double)pb[j*3+1];
        const double z = (double)pb[j*3+2];
        const double d2 = (ns2 + (x*x + y*y + z*z)) - 2.0*(x*sx + y*sy + z*sz);
        const bool inA = (d2 <= R2D + EPSD);
        const bool inB = (d2 <= R2D - EPSD);
        const unsigned long long mA = __ballot(inA);
        const unsigned long long mB = __ballot(inB);
        const unsigned long long below = (1ull << lane) - 1ull;
        if (cntA == 0 && mA) firstA = base + __builtin_ctzll(mA);
        if (cntB == 0 && mB) firstB = base + __builtin_ctzll(mB);
        if (inA) { const int pos = cntA + __popcll(mA & below); if (pos < KK) sA[wave][pos] = j; }
        if (inB) { const int pos = cntB + __popcll(mB & below); if (pos < KK) sB[wave][pos] = j; }
        cntA += __popcll(mA);
        cntB += __popcll(mB);
        if (cntB >= KK) break;
    }
    for (int q = cntA + lane; q < KK; q += 64) sA[wave][q] = firstA;
    for (int q = cntB + lane; q < KK; q += 64) sB[wave][q] = firstB;
    __syncthreads();
    const unsigned long long dm = __ballot(lane < KK && (sA[wave][lane] != sB[wave][lane]));
    int* outA = gA + ((size_t)b*NS + s)*KK;
    int* outB = gB + ((size_t)b*NS + s)*KK;
    if (lane < KK) { outA[lane] = sA[wave][lane]; outB[lane] = sB[wave][lane]; }
    if (lane == 0) flag[b*NS + s] = (dm != 0ull) ? 1 : 0;
}

// ---------------- 4. literal local branch (A or B set) ----------------
__global__ __launch_bounds__(256) void k_local(const float* __restrict__ p, const float* __restrict__ f,
    const float* __restrict__ newp, const float* __restrict__ fi, const int* __restrict__ gidx,
    const int* __restrict__ flag, const int mode,
    const float* __restrict__ w_convs, const float* __restrict__ s_convs, const float* __restrict__ b_convs,
    const float* __restrict__ w_attn_l, const float* __restrict__ s_attn_l, const float* __restrict__ b_attn_l,
    float* __restrict__ localf)
{
    const int s = blockIdx.x, b = blockIdx.y;
    if (mode && !flag[b*NS + s]) return;
    const int tid = threadIdx.x;
    __shared__ int   jg[KK];
    __shared__ float sfp[3][KK];
    __shared__ float sff[CC][KK];
    __shared__ float snp[3], sfi[CC];
    __shared__ float sE[OO][KK+1];   // +1 pad: kills 64-way bank conflict
    __shared__ float sDen[OO];
    if (tid < KK) jg[tid] = gidx[((size_t)b*NS + s)*KK + tid];
    if (tid >= 64 && tid < 67) snp[tid-64] = newp[((size_t)b*NS + s)*3 + (tid-64)];
    if (tid >= 128 && tid < 192) sfi[tid-128] = fi[((size_t)b*CC + (tid-128))*NS + s];
    __syncthreads();
    for (int i = tid; i < 3*KK; i += 256) { const int k = i & 31, d = i >> 5; sfp[d][k] = p[((size_t)b*NN + jg[k])*3 + d]; }
    for (int i = tid; i < CC*KK; i += 256) { const int k = i & 31, c = i >> 5; sff[c][k] = f[((size_t)b*CC + c)*NN + jg[k]]; }
    __syncthreads();
    const int o = tid & 127, mat = tid >> 7;
    const float* wrow = (mat ? w_attn_l : w_convs) + o*131;
    const float scale = mat ? s_attn_l[o] : s_convs[o];
    const float bias  = mat ? b_attn_l[o] : b_convs[o];
    const float wp0 = wrow[0], wp1 = wrow[1], wp2 = wrow[2];
    float acc[KK];
#pragma unroll
    for (int k = 0; k < KK; ++k)
        acc[k] = wp0*(sfp[0][k]-snp[0]) + wp1*(sfp[1][k]-snp[1]) + wp2*(sfp[2][k]-snp[2]);
    for (int c = 0; c < CC; ++c) {
        const float w2 = wrow[3+c], w3 = wrow[67+c], fic = sfi[c];
#pragma unroll
        for (int k = 0; k < KK; ++k) {
            const float fj = sff[c][k];
            acc[k] += w2*fj + w3*(fj - fic);
        }
    }
#pragma unroll
    for (int k = 0; k < KK; ++k) acc[k] = scale*acc[k] + bias;
    if (mat) {
        float mx = acc[0]*INV_TAU;
#pragma unroll
        for (int k = 1; k < KK; ++k) mx = fmaxf(mx, acc[k]*INV_TAU);
        float den = 0.f;
#pragma unroll
        for (int k = 0; k < KK; ++k) { const float e = expf(acc[k]*INV_TAU - mx); sE[o][k] = e; den += e; }
        sDen[o] = den;
    }
    __syncthreads();
    if (!mat) {
        const float den = sDen[o];
        float num = 0.f;
#pragma unroll
        for (int k = 0; k < KK; ++k) num += (sE[o][k]/den) * acc[k];
        localf[((size_t)b*OO + o)*NS + s] = num;
    }
}

// ---------------- 5. H (identity consumed; rest control) ----------------
__global__ __launch_bounds__(384) void k_H(const float* __restrict__ newp, const float* __restrict__ fi,
    const float* __restrict__ w_convs, const float* __restrict__ s_convs,
    const float* __restrict__ w_gconvs, const float* __restrict__ s_gconvs,
    const float* __restrict__ w_skip, const float* __restrict__ b_skip,
    float* __restrict__ H)
{
    const int b  = blockIdx.y;
    const int s0 = blockIdx.x * 32;
    const int tid = threadIdx.x;
    __shared__ float sfi[64][32];
    __shared__ float snp[3][32];
    for (int i = tid; i < 64*32; i += 384) {
        const int c = i >> 5, t = i & 31;
        sfi[c][t] = fi[((size_t)b*64 + c)*NS + s0 + t];
    }
    for (int i = tid; i < 96; i += 384) {
        const int d = i / 32, t = i % 32;
        snp[d][t] = newp[((size_t)b*NS + s0 + t)*3 + d];
    }
    __syncthreads();
    const int sec = tid >> 7, oo = tid & 127;
    float wp0 = 0.f, wp1 = 0.f, wp2 = 0.f, scale = 1.0f, bias = 0.0f;
    float wc[64];
    if (sec == 0) {
        const float* w = w_convs + oo*131;
        wp0 = w[0]; wp1 = w[1]; wp2 = w[2];
#pragma unroll
        for (int c = 0; c < 64; ++c) wc[c] = w[67+c];
        scale = s_convs[oo];
    } else if (sec == 1) {
        const float* w = w_gconvs + oo*131;
        wp0 = w[0]; wp1 = w[1]; wp2 = w[2];
#pragma unroll
        for (int c = 0; c < 64; ++c) wc[c] = w[67+c];
        scale = s_gconvs[oo];
    } else {
        const float* w = w_skip + oo*64;
#pragma unroll
        for (int c = 0; c < 64; ++c) wc[c] = w[c];
        bias = b_skip[oo];
    }
    float* Hout = H + ((size_t)b*NS + s0)*384 + tid;
#pragma unroll 1
    for (int t4 = 0; t4 < 8; ++t4) {
        const int t = t4*4;
        float a0 = wp0*snp[0][t+0] + wp1*snp[1][t+0] + wp2*snp[2][t+0];
        float a1 = wp0*snp[0][t+1] + wp1*snp[1][t+1] + wp2*snp[2][t+1];
        float a2 = wp0*snp[0][t+2] + wp1*snp[1][t+2] + wp2*snp[2][t+2];
        float a3 = wp0*snp[0][t+3] + wp1*snp[1][t+3] + wp2*snp[2][t+3];
#pragma unroll
        for (int c = 0; c < 64; ++c) {
            const float4 v = *reinterpret_cast<const float4*>(&sfi[c][t]);
            a0 += wc[c]*v.x; a1 += wc[c]*v.y; a2 += wc[c]*v.z; a3 += wc[c]*v.w;
        }
        Hout[(size_t)(t+0)*384] = scale*a0 + bias;
        Hout[(size_t)(t+1)*384] = scale*a1 + bias;
        Hout[(size_t)(t+2)*384] = scale*a2 + bias;
        Hout[(size_t)(t+3)*384] = scale*a3 + bias;
    }
}

// ---------------- 6a. imap softmax over n + global_p ----------------
__global__ __launch_bounds__(256) void k_gattn1(const float* __restrict__ fi, const float* __restrict__ z,
    const float* __restrict__ newp, float* __restrict__ probs, float* __restrict__ gp)
{
    const int m = blockIdx.x, b = blockIdx.y;
    const int tid = threadIdx.x;
    __shared__ float zr[64];
    __shared__ float r0[4], r1[4], r2[4], r3[4];
    __shared__ float bcast[2];
    if (tid < 64) zr[tid] = z[m*64 + tid];
    __syncthreads();
    float v0=0,v1=0,v2=0,v3=0;
    for (int c = 0; c < 64; ++c) {
        const float zc = zr[c];
        const float* fr = fi + ((size_t)b*64 + c)*NS;
        v0 += zc * fr[tid];
        v1 += zc * fr[tid + 256];
        v2 += zc * fr[tid + 512];
        v3 += zc * fr[tid + 768];
    }
    float mx = fmaxf(fmaxf(v0,v1), fmaxf(v2,v3));
    mx = wave_max_f(mx);
    if ((tid&63)==0) r0[tid>>6] = mx;
    __syncthreads();
    if (tid == 0) bcast[0] = fmaxf(fmaxf(r0[0],r0[1]), fmaxf(r0[2],r0[3]));
    __syncthreads();
    mx = bcast[0];
    const float e0 = expf(v0-mx), e1 = expf(v1-mx), e2 = expf(v2-mx), e3 = expf(v3-mx);
    float sum = wave_sum_f(e0+e1+e2+e3);
    if ((tid&63)==0) r0[tid>>6] = sum;
    __syncthreads();
    if (tid == 0) bcast[1] = r0[0]+r0[1]+r0[2]+r0[3];
    __syncthreads();
    const float denom = bcast[1];
    float px=0, py=0, pz=0;
    const float ee[4] = {e0,e1,e2,e3};
#pragma unroll
    for (int q = 0; q < 4; ++q) {
        const int n = tid + q*256;
        const float pn = ee[q] / denom;
        probs[((size_t)b*MM + m)*NS + n] = pn;
        px += pn * newp[((size_t)b*NS+n)*3+0];
        py += pn * newp[((size_t)b*NS+n)*3+1];
        pz += pn * newp[((size_t)b*NS+n)*3+2];
    }
    px = wave_sum_f(px); py = wave_sum_f(py); pz = wave_sum_f(pz);
    if ((tid&63)==0) { r1[tid>>6]=px; r2[tid>>6]=py; r3[tid>>6]=pz; }
    __syncthreads();
    if (tid == 0) {
        gp[((size_t)b*MM+m)*3+0] = r1[0]+r1[1]+r1[2]+r1[3];
        gp[((size_t)b*MM+m)*3+1] = r2[0]+r2[1]+r2[2]+r2[3];
        gp[((size_t)b*MM+m)*3+2] = r3[0]+r3[1]+r3[2]+r3[3];
    }
}

// ---------------- 6b. gaussian kernel attn + global_f ----------------
__global__ __launch_bounds__(256) void k_gattn2(const float* __restrict__ fi, const float* __restrict__ newp,
    const float* __restrict__ probs, const float* __restrict__ gp, float* __restrict__ gf)
{
    const int m = blockIdx.x, b = blockIdx.y;
    const int tid = threadIdx.x;
    __shared__ float at[NS];
    __shared__ float part[64][4];
    const float gx = gp[((size_t)b*MM+m)*3+0];
    const float gy = gp[((size_t)b*MM+m)*3+1];
    const float gz = gp[((size_t)b*MM+m)*3+2];
    const float g2 = gx*gx + gy*gy + gz*gz;
#pragma unroll
    for (int q = 0; q < 4; ++q) {
        const int n = tid + q*256;
        const float nx = newp[((size_t)b*NS+n)*3+0];
        const float ny = newp[((size_t)b*NS+n)*3+1];
        const float nz = newp[((size_t)b*NS+n)*3+2];
        const float n2 = nx*nx + ny*ny + nz*nz;
        float dot = gx*nx; dot += gy*ny; dot += gz*nz;
        const float d2 = fmaxf((g2 + n2) - 2.0f*dot, 0.0f);
        at[n] = probs[((size_t)b*MM+m)*NS+n] * expf(-GAMMA_C*d2);
    }
    __syncthreads();
    const int d = tid >> 2, q = tid & 3;
    const float* fr = fi + ((size_t)b*64 + d)*NS + q*256;
    const float* ar = at + q*256;
    float acc = 0.f;
    for (int i = 0; i < 256; i += 4) {
        const float4 fv = *reinterpret_cast<const float4*>(fr + i);
        acc += fv.x*ar[i] + fv.y*ar[i+1] + fv.z*ar[i+2] + fv.w*ar[i+3];
    }
    part[d][q] = acc;
    __syncthreads();
    if (tid < 64) gf[((size_t)b*64 + tid)*MM + m] = part[tid][0]+part[tid][1]+part[tid][2]+part[tid][3];
}

// ---------------- 6c. literal global_out ----------------
__global__ __launch_bounds__(256) void k_gout(const float* __restrict__ gp, const float* __restrict__ gf,
    const float* __restrict__ newp, const float* __restrict__ fi,
    const float* __restrict__ w_gconvs, const float* __restrict__ s_gconvs, const float* __restrict__ b_gconvs,
    const float* __restrict__ w_attn_g, const float* __restrict__ s_attn_g, const float* __restrict__ b_attn_g,
    float* __restrict__ gout)
{
    const int s = blockIdx.x, b = blockIdx.y;
    const int tid = threadIdx.x;
    __shared__ float sgf[CC][MM];
    __shared__ float sgp[MM][3];
    __shared__ float snp[3], sfi[CC];
    __shared__ float sE[OO][MM+1];   // +1 pad: kills bank conflict
    __shared__ float sDen[OO];
    for (int i = tid; i < CC*MM; i += 256) { const int c = i >> 4, m = i & 15; sgf[c][m] = gf[((size_t)b*CC + c)*MM + m]; }
    if (tid < MM*3) sgp[tid/3][tid%3] = gp[(size_t)b*MM*3 + tid];
    if (tid >= 64 && tid < 67) snp[tid-64] = newp[((size_t)b*NS + s)*3 + (tid-64)];
    if (tid >= 128 && tid < 192) sfi[tid-128] = fi[((size_t)b*CC + (tid-128))*NS + s];
    __syncthreads();
    const int o = tid & 127, mat = tid >> 7;
    const float* wrow = (mat ? w_attn_g : w_gconvs) + o*131;
    const float scale = mat ? s_attn_g[o] : s_gconvs[o];
    const float bias  = mat ? b_attn_g[o] : b_gconvs[o];
    const float wp0 = wrow[0], wp1 = wrow[1], wp2 = wrow[2];
    float acc[MM];
#pragma unroll
    for (int m = 0; m < MM; ++m)
        acc[m] = wp0*(sgp[m][0]-snp[0]) + wp1*(sgp[m][1]-snp[1]) + wp2*(sgp[m][2]-snp[2]);
    for (int c = 0; c < CC; ++c) {
        const float w2 = wrow[3+c], w3 = wrow[67+c], fic = sfi[c];
#pragma unroll
        for (int m = 0; m < MM; ++m) {
            const float gv = sgf[c][m];
            acc[m] += w2*gv + w3*(gv - fic);
        }
    }
#pragma unroll
    for (int m = 0; m < MM; ++m) acc[m] = scale*acc[m] + bias;
    if (mat) {
        float mx = acc[0]*INV_TAU;
#pragma unroll
        for (int m = 1; m < MM; ++m) mx = fmaxf(mx, acc[m]*INV_TAU);
        float den = 0.f;
#pragma unroll
        for (int m = 0; m < MM; ++m) { const float e = expf(acc[m]*INV_TAU - mx); sE[o][m] = e; den += e; }
        sDen[o] = den;
    }
    __syncthreads();
    if (!mat) {
        const float den = sDen[o];
        float num = 0.f;
#pragma unroll
        for (int m = 0; m < MM; ++m) num += (sE[o][m]/den) * acc[m];
        gout[((size_t)b*OO + o)*NS + s] = num;
    }
}

// ---------------- 7. final combine (marginal-average) ----------------
__global__ __launch_bounds__(256) void k_final(const float* __restrict__ lfA, const float* __restrict__ lfB,
    const int* __restrict__ flag, const float* __restrict__ gout,
    const float* __restrict__ H, const float* __restrict__ alpha,
    float* __restrict__ outp)
{
    const int b  = blockIdx.y;
    const int s0 = blockIdx.x * 2;
    const int tid = threadIdx.x;
    const int o = tid & 127, si = tid >> 7;
    const int s = s0 + si;
    const float idv = H[((size_t)b*NS + s)*384 + 256 + o];
    const float a   = 1.0f / (1.0f + expf(-alpha[0]));
    const size_t li = ((size_t)b*OO + o)*NS + s;
    float lf = lfA[li];
    if (flag[b*NS + s]) lf = 0.5f*(lf + lfB[li]);
    const float go  = gout[li];
    const float v   = lf*(1.0f - a) + go*a + idv;
    outp[NP_ELEMS + li] = fmaxf(v, 0.0f);
}

extern "C" void kernel_launch(void* const* d_in, const int* in_sizes, int n_in,
                              void* d_out, int out_size, void* d_ws, size_t ws_size,
                              hipStream_t stream)
{
    const float* p        = (const float*)d_in[0];
    const float* f        = (const float*)d_in[1];
    const float* w_convs  = (const float*)d_in[2];
    const float* s_convs  = (const float*)d_in[3];
    const float* b_convs  = (const float*)d_in[4];
    const float* w_attn_l = (const float*)d_in[5];
    const float* s_attn_l = (const float*)d_in[6];
    const float* b_attn_l = (const float*)d_in[7];
    const float* w_gconvs = (const float*)d_in[8];
    const float* s_gconvs = (const float*)d_in[9];
    const float* b_gconvs = (const float*)d_in[10];
    const float* w_attn_g = (const float*)d_in[11];
    const float* s_attn_g = (const float*)d_in[12];
    const float* b_attn_g = (const float*)d_in[13];
    const float* w_skip   = (const float*)d_in[14];
    const float* b_skip   = (const float*)d_in[15];
    const float* z        = (const float*)d_in[16];
    const float* alpha    = (const float*)d_in[17];

    float* out = (float*)d_out;
    float* ws  = (float*)d_ws;
    float* lfA   = ws + WS_LFA;
    float* lfB   = ws + WS_LFB;
    float* gout  = ws + WS_GO;
    float* H     = ws + WS_H;
    float* fi    = ws + WS_FI;
    int*   idx   = (int*)(ws + WS_IDX);
    int*   gidxA = (int*)(ws + WS_GIDXA);
    int*   gidxB = (int*)(ws + WS_GIDXB);
    int*   flag  = (int*)(ws + WS_FLAG);
    float* probs = ws + WS_PROBS;
    float* gp    = ws + WS_GP;
    float* gf    = ws + WS_GF;
    float* newp  = out;

    hipLaunchKernelGGL(k_fps,       dim3(BB),         dim3(512),  0, stream, p, idx, newp);
    hipLaunchKernelGGL(k_gather_fi, dim3(BB*64),      dim3(256),  0, stream, f, idx, fi);
    hipLaunchKernelGGL(k_ball2,     dim3(NS/4, BB),   dim3(256),  0, stream, p, newp, gidxA, gidxB, flag);
    hipLaunchKernelGGL(k_local,     dim3(NS, BB),     dim3(256),  0, stream, p, f, newp, fi, gidxA, flag, 0,
                       w_convs, s_convs, b_convs, w_attn_l, s_attn_l, b_attn_l, lfA);
    hipLaunchKernelGGL(k_local,     dim3(NS, BB),     dim3(256),  0, stream, p, f, newp, fi, gidxB, flag, 1,
                       w_convs, s_convs, b_convs, w_attn_l, s_attn_l, b_attn_l, lfB);
    hipLaunchKernelGGL(k_H,         dim3(NS/32, BB),  dim3(384),  0, stream, newp, fi,
                       w_convs, s_convs, w_gconvs, s_gconvs, w_skip, b_skip, H);
    hipLaunchKernelGGL(k_gattn1,    dim3(MM, BB),     dim3(256),  0, stream, fi, z, newp, probs, gp);
    hipLaunchKernelGGL(k_gattn2,    dim3(MM, BB),     dim3(256),  0, stream, fi, newp, probs, gp, gf);
    hipLaunchKernelGGL(k_gout,      dim3(NS, BB),     dim3(256),  0, stream, gp, gf, newp, fi,
                       w_gconvs, s_gconvs, b_gconvs, w_attn_g, s_attn_g, b_attn_g, gout);
    hipLaunchKernelGGL(k_final,     dim3(NS/2, BB),   dim3(256),  0, stream, lfA, lfB, flag, gout, H, alpha, out);
}

// Round 11
// 2486.349 us; speedup vs baseline: 1.1784x; 1.1784x over previous
//
#include <hip/hip_runtime.h>
#include <hip/hip_bf16.h>
#include <math.h>

#define BB 8
#define NN 4096
#define NS 1024
#define CC 64
#define OO 128
#define MM 16
#define GAMMA_C 16.0f
#define INV_TAU 1.0f
#define KK 32
#define NP_ELEMS (BB*NS*3)

// ---- workspace layout (units: 4-byte elements) ----
#define WS_LFA   0                           // float[B*O*NS]
#define WS_LFB   (WS_LFA + BB*OO*NS)         // float[B*O*NS]
#define WS_GO    (WS_LFB + BB*OO*NS)         // float[B*O*NS]
#define WS_H     (WS_GO + BB*OO*NS)          // float[B*NS*384]
#define WS_FI    (WS_H + BB*NS*384)          // float[B*C*NS]
#define WS_IDX   (WS_FI + BB*CC*NS)          // int[B*NS]
#define WS_GIDXA (WS_IDX + BB*NS)            // int[B*NS*K]
#define WS_GIDXB (WS_GIDXA + BB*NS*KK)       // int[B*NS*K]
#define WS_FLAG  (WS_GIDXB + BB*NS*KK)       // int[B*NS]
#define WS_PROBS (WS_FLAG + BB*NS)           // float[B*M*NS]
#define WS_GP    (WS_PROBS + BB*MM*NS)       // float[B*M*3]
#define WS_GF    (WS_GP + BB*MM*3)           // float[B*C*M]

__device__ inline float wave_max_f(float v) {
#pragma unroll
    for (int o = 32; o; o >>= 1) v = fmaxf(v, __shfl_xor(v, o, 64));
    return v;
}
__device__ inline float wave_sum_f(float v) {
#pragma unroll
    for (int o = 32; o; o >>= 1) v += __shfl_xor(v, o, 64);
    return v;
}

// DPP-based packed (distbits, ~idx) max step. Positive f32 order == uint
// order; lo = ~idx tie-breaks to the SMALLEST index (numpy argmax
// first-occurrence). bound_ctrl=1: unwritten lanes read 0 = losing candidate.
template<int CTRL>
__device__ inline void dpp_max_step(unsigned& hi, unsigned& lo) {
    const unsigned nh = (unsigned)__builtin_amdgcn_mov_dpp((int)hi, CTRL, 0xF, 0xF, true);
    const unsigned nl = (unsigned)__builtin_amdgcn_mov_dpp((int)lo, CTRL, 0xF, 0xF, true);
    if (nh > hi || (nh == hi && nl > lo)) { hi = nh; lo = nl; }
}
#define ROR1  0x121
#define ROR2  0x122
#define ROR4  0x124
#define ROR8  0x128
#define BC15  0x142
#define BC31  0x143

// ---------------- 1. Farthest point sampling ----------------
// 1024 threads (16 waves: TLP hides chain latency) + 4 points/thread in
// REGISTERS (no per-iteration LDS point reads — that was R8's 1100cy/iter
// LDS-pipe cost) + lean 2-value packed DPP reduce (R10's 5-wide carry
// lengthened the chain 2.5x). px[last] via uniform LDS read. Literal-order
// f32 distances (contract off) + total-order packed max => bit-identical
// argmax decisions regardless of partition/topology.
__global__ __launch_bounds__(1024) void k_fps(const float* __restrict__ p,
                                              int* __restrict__ idx_out,
                                              float* __restrict__ newp)
{
#pragma clang fp contract(off)
    const int b    = blockIdx.x;
    const int tid  = threadIdx.x;
    const int lane = tid & 63;
    const int wave = tid >> 6;     // 0..15
    __shared__ float px[NN], py[NN], pz[NN];
    __shared__ unsigned phi[2][16], plo[2][16];
    __shared__ int sidx[NS];
    const float* pb = p + (size_t)b*NN*3;
    float pxr[4], pyr[4], pzr[4], dd[4];
#pragma unroll
    for (int q = 0; q < 4; ++q) {
        const int j = tid + q*1024;
        const float x = pb[j*3+0], y = pb[j*3+1], z = pb[j*3+2];
        px[j] = x; py[j] = y; pz[j] = z;
        pxr[q] = x; pyr[q] = y; pzr[q] = z;
        dd[q] = 1e10f;
    }
    if (tid == 0) sidx[0] = 0;
    __syncthreads();
    int last = 0;
    for (int it = 1; it < NS; ++it) {
        const float lx = px[last], ly = py[last], lz = pz[last];
        unsigned bh = 0u, bl = 0u;
#pragma unroll
        for (int q = 0; q < 4; ++q) {
            const float dx = pxr[q]-lx, dy = pyr[q]-ly, dz = pzr[q]-lz;
            const float d = dx*dx + dy*dy + dz*dz;
            dd[q] = fminf(dd[q], d);
            const unsigned ch = __float_as_uint(dd[q]);
            const unsigned cl = ~(unsigned)(tid + q*1024);
            if (ch > bh || (ch == bh && cl > bl)) { bh = ch; bl = cl; }
        }
        // wave reduce: 4 ror steps (row of 16) + 2 bcast (cross-row)
        dpp_max_step<ROR1>(bh, bl);
        dpp_max_step<ROR2>(bh, bl);
        dpp_max_step<ROR4>(bh, bl);
        dpp_max_step<ROR8>(bh, bl);
        dpp_max_step<BC15>(bh, bl);
        dpp_max_step<BC31>(bh, bl);   // lane 63 holds the wave max
        const int buf = it & 1;
        if (lane == 63) { phi[buf][wave] = bh; plo[buf][wave] = bl; }
        __syncthreads();
        // all waves redundantly reduce the 16 partials
        unsigned h2 = phi[buf][lane & 15], l2 = plo[buf][lane & 15];
        dpp_max_step<ROR1>(h2, l2);
        dpp_max_step<ROR2>(h2, l2);
        dpp_max_step<ROR4>(h2, l2);
        dpp_max_step<ROR8>(h2, l2);
        last = (int)(~l2);
        if (tid == 0) sidx[it] = last;
    }
    __syncthreads();
    for (int s = tid; s < NS; s += 1024) {
        const int j = sidx[s];
        idx_out[b*NS + s] = j;
        newp[((size_t)b*NS + s)*3 + 0] = px[j];
        newp[((size_t)b*NS + s)*3 + 1] = py[j];
        newp[((size_t)b*NS + s)*3 + 2] = pz[j];
    }
}

// ---------------- 2. gather fi ----------------
__global__ __launch_bounds__(256) void k_gather_fi(const float* __restrict__ f,
                                                   const int* __restrict__ idx,
                                                   float* __restrict__ fi)
{
    const int bc = blockIdx.x;
    const int b  = bc >> 6;
    const float* frow = f + (size_t)bc * NN;
    float* firow = fi + (size_t)bc * NS;
    const int* ib = idx + b*NS;
    for (int s = threadIdx.x; s < NS; s += 256) firow[s] = frow[ib[s]];
}

// ---------------- 3. ball query with marginal-pair dual sets ----------------
__global__ __launch_bounds__(256) void k_ball2(const float* __restrict__ p,
                                               const float* __restrict__ newp,
                                               int* __restrict__ gA, int* __restrict__ gB,
                                               int* __restrict__ flag)
{
    const int b    = blockIdx.y;
    const int wave = threadIdx.x >> 6;
    const int lane = threadIdx.x & 63;
    const int s    = blockIdx.x * 4 + wave;
    __shared__ int sA[4][KK], sB[4][KK];
    const float* pb = p + (size_t)b*NN*3;
    const double sx = (double)newp[((size_t)b*NS+s)*3+0];
    const double sy = (double)newp[((size_t)b*NS+s)*3+1];
    const double sz = (double)newp[((size_t)b*NS+s)*3+2];
    const double ns2 = sx*sx + sy*sy + sz*sz;
    const double R2D = (double)(0.0225f);
    const double EPSD = 1.5e-7;
    int cntA = 0, cntB = 0, firstA = 0, firstB = 0;
    for (int base = 0; base < NN; base += 64) {
        const int j = base + lane;
        const double x = (double)pb[j*3+0];
        const double y = (double)pb[j*3+1];
        const double z = (double)pb[j*3+2];
        const double d2 = (ns2 + (x*x + y*y + z*z)) - 2.0*(x*sx + y*sy + z*sz);
        const bool inA = (d2 <= R2D + EPSD);
        const bool inB = (d2 <= R2D - EPSD);
        const unsigned long long mA = __ballot(inA);
        const unsigned long long mB = __ballot(inB);
        const unsigned long long below = (1ull << lane) - 1ull;
        if (cntA == 0 && mA) firstA = base + __builtin_ctzll(mA);
        if (cntB == 0 && mB) firstB = base + __builtin_ctzll(mB);
        if (inA) { const int pos = cntA + __popcll(mA & below); if (pos < KK) sA[wave][pos] = j; }
        if (inB) { const int pos = cntB + __popcll(mB & below); if (pos < KK) sB[wave][pos] = j; }
        cntA += __popcll(mA);
        cntB += __popcll(mB);
        if (cntB >= KK) break;
    }
    for (int q = cntA + lane; q < KK; q += 64) sA[wave][q] = firstA;
    for (int q = cntB + lane; q < KK; q += 64) sB[wave][q] = firstB;
    __syncthreads();
    const unsigned long long dm = __ballot(lane < KK && (sA[wave][lane] != sB[wave][lane]));
    int* outA = gA + ((size_t)b*NS + s)*KK;
    int* outB = gB + ((size_t)b*NS + s)*KK;
    if (lane < KK) { outA[lane] = sA[wave][lane]; outB[lane] = sB[wave][lane]; }
    if (lane == 0) flag[b*NS + s] = (dm != 0ull) ? 1 : 0;
}

// ---------------- 4. literal local branch (A or B set) ----------------
__global__ __launch_bounds__(256) void k_local(const float* __restrict__ p, const float* __restrict__ f,
    const float* __restrict__ newp, const float* __restrict__ fi, const int* __restrict__ gidx,
    const int* __restrict__ flag, const int mode,
    const float* __restrict__ w_convs, const float* __restrict__ s_convs, const float* __restrict__ b_convs,
    const float* __restrict__ w_attn_l, const float* __restrict__ s_attn_l, const float* __restrict__ b_attn_l,
    float* __restrict__ localf)
{
    const int s = blockIdx.x, b = blockIdx.y;
    if (mode && !flag[b*NS + s]) return;
    const int tid = threadIdx.x;
    __shared__ int   jg[KK];
    __shared__ float sfp[3][KK];
    __shared__ float sff[CC][KK];
    __shared__ float snp[3], sfi[CC];
    __shared__ float sE[OO][KK+1];   // +1 pad: kills 64-way bank conflict
    __shared__ float sDen[OO];
    if (tid < KK) jg[tid] = gidx[((size_t)b*NS + s)*KK + tid];
    if (tid >= 64 && tid < 67) snp[tid-64] = newp[((size_t)b*NS + s)*3 + (tid-64)];
    if (tid >= 128 && tid < 192) sfi[tid-128] = fi[((size_t)b*CC + (tid-128))*NS + s];
    __syncthreads();
    for (int i = tid; i < 3*KK; i += 256) { const int k = i & 31, d = i >> 5; sfp[d][k] = p[((size_t)b*NN + jg[k])*3 + d]; }
    for (int i = tid; i < CC*KK; i += 256) { const int k = i & 31, c = i >> 5; sff[c][k] = f[((size_t)b*CC + c)*NN + jg[k]]; }
    __syncthreads();
    const int o = tid & 127, mat = tid >> 7;
    const float* wrow = (mat ? w_attn_l : w_convs) + o*131;
    const float scale = mat ? s_attn_l[o] : s_convs[o];
    const float bias  = mat ? b_attn_l[o] : b_convs[o];
    const float wp0 = wrow[0], wp1 = wrow[1], wp2 = wrow[2];
    float acc[KK];
#pragma unroll
    for (int k = 0; k < KK; ++k)
        acc[k] = wp0*(sfp[0][k]-snp[0]) + wp1*(sfp[1][k]-snp[1]) + wp2*(sfp[2][k]-snp[2]);
    for (int c = 0; c < CC; ++c) {
        const float w2 = wrow[3+c], w3 = wrow[67+c], fic = sfi[c];
#pragma unroll
        for (int k = 0; k < KK; ++k) {
            const float fj = sff[c][k];
            acc[k] += w2*fj + w3*(fj - fic);
        }
    }
#pragma unroll
    for (int k = 0; k < KK; ++k) acc[k] = scale*acc[k] + bias;
    if (mat) {
        float mx = acc[0]*INV_TAU;
#pragma unroll
        for (int k = 1; k < KK; ++k) mx = fmaxf(mx, acc[k]*INV_TAU);
        float den = 0.f;
#pragma unroll
        for (int k = 0; k < KK; ++k) { const float e = expf(acc[k]*INV_TAU - mx); sE[o][k] = e; den += e; }
        sDen[o] = den;
    }
    __syncthreads();
    if (!mat) {
        const float den = sDen[o];
        float num = 0.f;
#pragma unroll
        for (int k = 0; k < KK; ++k) num += (sE[o][k]/den) * acc[k];
        localf[((size_t)b*OO + o)*NS + s] = num;
    }
}

// ---------------- 5. H (identity consumed; rest control) ----------------
__global__ __launch_bounds__(384) void k_H(const float* __restrict__ newp, const float* __restrict__ fi,
    const float* __restrict__ w_convs, const float* __restrict__ s_convs,
    const float* __restrict__ w_gconvs, const float* __restrict__ s_gconvs,
    const float* __restrict__ w_skip, const float* __restrict__ b_skip,
    float* __restrict__ H)
{
    const int b  = blockIdx.y;
    const int s0 = blockIdx.x * 32;
    const int tid = threadIdx.x;
    __shared__ float sfi[64][32];
    __shared__ float snp[3][32];
    for (int i = tid; i < 64*32; i += 384) {
        const int c = i >> 5, t = i & 31;
        sfi[c][t] = fi[((size_t)b*64 + c)*NS + s0 + t];
    }
    for (int i = tid; i < 96; i += 384) {
        const int d = i / 32, t = i % 32;
        snp[d][t] = newp[((size_t)b*NS + s0 + t)*3 + d];
    }
    __syncthreads();
    const int sec = tid >> 7, oo = tid & 127;
    float wp0 = 0.f, wp1 = 0.f, wp2 = 0.f, scale = 1.0f, bias = 0.0f;
    float wc[64];
    if (sec == 0) {
        const float* w = w_convs + oo*131;
        wp0 = w[0]; wp1 = w[1]; wp2 = w[2];
#pragma unroll
        for (int c = 0; c < 64; ++c) wc[c] = w[67+c];
        scale = s_convs[oo];
    } else if (sec == 1) {
        const float* w = w_gconvs + oo*131;
        wp0 = w[0]; wp1 = w[1]; wp2 = w[2];
#pragma unroll
        for (int c = 0; c < 64; ++c) wc[c] = w[67+c];
        scale = s_gconvs[oo];
    } else {
        const float* w = w_skip + oo*64;
#pragma unroll
        for (int c = 0; c < 64; ++c) wc[c] = w[c];
        bias = b_skip[oo];
    }
    float* Hout = H + ((size_t)b*NS + s0)*384 + tid;
#pragma unroll 1
    for (int t4 = 0; t4 < 8; ++t4) {
        const int t = t4*4;
        float a0 = wp0*snp[0][t+0] + wp1*snp[1][t+0] + wp2*snp[2][t+0];
        float a1 = wp0*snp[0][t+1] + wp1*snp[1][t+1] + wp2*snp[2][t+1];
        float a2 = wp0*snp[0][t+2] + wp1*snp[1][t+2] + wp2*snp[2][t+2];
        float a3 = wp0*snp[0][t+3] + wp1*snp[1][t+3] + wp2*snp[2][t+3];
#pragma unroll
        for (int c = 0; c < 64; ++c) {
            const float4 v = *reinterpret_cast<const float4*>(&sfi[c][t]);
            a0 += wc[c]*v.x; a1 += wc[c]*v.y; a2 += wc[c]*v.z; a3 += wc[c]*v.w;
        }
        Hout[(size_t)(t+0)*384] = scale*a0 + bias;
        Hout[(size_t)(t+1)*384] = scale*a1 + bias;
        Hout[(size_t)(t+2)*384] = scale*a2 + bias;
        Hout[(size_t)(t+3)*384] = scale*a3 + bias;
    }
}

// ---------------- 6a. imap softmax over n + global_p ----------------
__global__ __launch_bounds__(256) void k_gattn1(const float* __restrict__ fi, const float* __restrict__ z,
    const float* __restrict__ newp, float* __restrict__ probs, float* __restrict__ gp)
{
    const int m = blockIdx.x, b = blockIdx.y;
    const int tid = threadIdx.x;
    __shared__ float zr[64];
    __shared__ float r0[4], r1[4], r2[4], r3[4];
    __shared__ float bcast[2];
    if (tid < 64) zr[tid] = z[m*64 + tid];
    __syncthreads();
    float v0=0,v1=0,v2=0,v3=0;
    for (int c = 0; c < 64; ++c) {
        const float zc = zr[c];
        const float* fr = fi + ((size_t)b*64 + c)*NS;
        v0 += zc * fr[tid];
        v1 += zc * fr[tid + 256];
        v2 += zc * fr[tid + 512];
        v3 += zc * fr[tid + 768];
    }
    float mx = fmaxf(fmaxf(v0,v1), fmaxf(v2,v3));
    mx = wave_max_f(mx);
    if ((tid&63)==0) r0[tid>>6] = mx;
    __syncthreads();
    if (tid == 0) bcast[0] = fmaxf(fmaxf(r0[0],r0[1]), fmaxf(r0[2],r0[3]));
    __syncthreads();
    mx = bcast[0];
    const float e0 = expf(v0-mx), e1 = expf(v1-mx), e2 = expf(v2-mx), e3 = expf(v3-mx);
    float sum = wave_sum_f(e0+e1+e2+e3);
    if ((tid&63)==0) r0[tid>>6] = sum;
    __syncthreads();
    if (tid == 0) bcast[1] = r0[0]+r0[1]+r0[2]+r0[3];
    __syncthreads();
    const float denom = bcast[1];
    float px=0, py=0, pz=0;
    const float ee[4] = {e0,e1,e2,e3};
#pragma unroll
    for (int q = 0; q < 4; ++q) {
        const int n = tid + q*256;
        const float pn = ee[q] / denom;
        probs[((size_t)b*MM + m)*NS + n] = pn;
        px += pn * newp[((size_t)b*NS+n)*3+0];
        py += pn * newp[((size_t)b*NS+n)*3+1];
        pz += pn * newp[((size_t)b*NS+n)*3+2];
    }
    px = wave_sum_f(px); py = wave_sum_f(py); pz = wave_sum_f(pz);
    if ((tid&63)==0) { r1[tid>>6]=px; r2[tid>>6]=py; r3[tid>>6]=pz; }
    __syncthreads();
    if (tid == 0) {
        gp[((size_t)b*MM+m)*3+0] = r1[0]+r1[1]+r1[2]+r1[3];
        gp[((size_t)b*MM+m)*3+1] = r2[0]+r2[1]+r2[2]+r2[3];
        gp[((size_t)b*MM+m)*3+2] = r3[0]+r3[1]+r3[2]+r3[3];
    }
}

// ---------------- 6b. gaussian kernel attn + global_f ----------------
__global__ __launch_bounds__(256) void k_gattn2(const float* __restrict__ fi, const float* __restrict__ newp,
    const float* __restrict__ probs, const float* __restrict__ gp, float* __restrict__ gf)
{
    const int m = blockIdx.x, b = blockIdx.y;
    const int tid = threadIdx.x;
    __shared__ float at[NS];
    __shared__ float part[64][4];
    const float gx = gp[((size_t)b*MM+m)*3+0];
    const float gy = gp[((size_t)b*MM+m)*3+1];
    const float gz = gp[((size_t)b*MM+m)*3+2];
    const float g2 = gx*gx + gy*gy + gz*gz;
#pragma unroll
    for (int q = 0; q < 4; ++q) {
        const int n = tid + q*256;
        const float nx = newp[((size_t)b*NS+n)*3+0];
        const float ny = newp[((size_t)b*NS+n)*3+1];
        const float nz = newp[((size_t)b*NS+n)*3+2];
        const float n2 = nx*nx + ny*ny + nz*nz;
        float dot = gx*nx; dot += gy*ny; dot += gz*nz;
        const float d2 = fmaxf((g2 + n2) - 2.0f*dot, 0.0f);
        at[n] = probs[((size_t)b*MM+m)*NS+n] * expf(-GAMMA_C*d2);
    }
    __syncthreads();
    const int d = tid >> 2, q = tid & 3;
    const float* fr = fi + ((size_t)b*64 + d)*NS + q*256;
    const float* ar = at + q*256;
    float acc = 0.f;
    for (int i = 0; i < 256; i += 4) {
        const float4 fv = *reinterpret_cast<const float4*>(fr + i);
        acc += fv.x*ar[i] + fv.y*ar[i+1] + fv.z*ar[i+2] + fv.w*ar[i+3];
    }
    part[d][q] = acc;
    __syncthreads();
    if (tid < 64) gf[((size_t)b*64 + tid)*MM + m] = part[tid][0]+part[tid][1]+part[tid][2]+part[tid][3];
}

// ---------------- 6c. literal global_out ----------------
__global__ __launch_bounds__(256) void k_gout(const float* __restrict__ gp, const float* __restrict__ gf,
    const float* __restrict__ newp, const float* __restrict__ fi,
    const float* __restrict__ w_gconvs, const float* __restrict__ s_gconvs, const float* __restrict__ b_gconvs,
    const float* __restrict__ w_attn_g, const float* __restrict__ s_attn_g, const float* __restrict__ b_attn_g,
    float* __restrict__ gout)
{
    const int s = blockIdx.x, b = blockIdx.y;
    const int tid = threadIdx.x;
    __shared__ float sgf[CC][MM];
    __shared__ float sgp[MM][3];
    __shared__ float snp[3], sfi[CC];
    __shared__ float sE[OO][MM+1];   // +1 pad: kills bank conflict
    __shared__ float sDen[OO];
    for (int i = tid; i < CC*MM; i += 256) { const int c = i >> 4, m = i & 15; sgf[c][m] = gf[((size_t)b*CC + c)*MM + m]; }
    if (tid < MM*3) sgp[tid/3][tid%3] = gp[(size_t)b*MM*3 + tid];
    if (tid >= 64 && tid < 67) snp[tid-64] = newp[((size_t)b*NS + s)*3 + (tid-64)];
    if (tid >= 128 && tid < 192) sfi[tid-128] = fi[((size_t)b*CC + (tid-128))*NS + s];
    __syncthreads();
    const int o = tid & 127, mat = tid >> 7;
    const float* wrow = (mat ? w_attn_g : w_gconvs) + o*131;
    const float scale = mat ? s_attn_g[o] : s_gconvs[o];
    const float bias  = mat ? b_attn_g[o] : b_gconvs[o];
    const float wp0 = wrow[0], wp1 = wrow[1], wp2 = wrow[2];
    float acc[MM];
#pragma unroll
    for (int m = 0; m < MM; ++m)
        acc[m] = wp0*(sgp[m][0]-snp[0]) + wp1*(sgp[m][1]-snp[1]) + wp2*(sgp[m][2]-snp[2]);
    for (int c = 0; c < CC; ++c) {
        const float w2 = wrow[3+c], w3 = wrow[67+c], fic = sfi[c];
#pragma unroll
        for (int m = 0; m < MM; ++m) {
            const float gv = sgf[c][m];
            acc[m] += w2*gv + w3*(gv - fic);
        }
    }
#pragma unroll
    for (int m = 0; m < MM; ++m) acc[m] = scale*acc[m] + bias;
    if (mat) {
        float mx = acc[0]*INV_TAU;
#pragma unroll
        for (int m = 1; m < MM; ++m) mx = fmaxf(mx, acc[m]*INV_TAU);
        float den = 0.f;
#pragma unroll
        for (int m = 0; m < MM; ++m) { const float e = expf(acc[m]*INV_TAU - mx); sE[o][m] = e; den += e; }
        sDen[o] = den;
    }
    __syncthreads();
    if (!mat) {
        const float den = sDen[o];
        float num = 0.f;
#pragma unroll
        for (int m = 0; m < MM; ++m) num += (sE[o][m]/den) * acc[m];
        gout[((size_t)b*OO + o)*NS + s] = num;
    }
}

// ---------------- 7. final combine (marginal-average) ----------------
__global__ __launch_bounds__(256) void k_final(const float* __restrict__ lfA, const float* __restrict__ lfB,
    const int* __restrict__ flag, const float* __restrict__ gout,
    const float* __restrict__ H, const float* __restrict__ alpha,
    float* __restrict__ outp)
{
    const int b  = blockIdx.y;
    const int s0 = blockIdx.x * 2;
    const int tid = threadIdx.x;
    const int o = tid & 127, si = tid >> 7;
    const int s = s0 + si;
    const float idv = H[((size_t)b*NS + s)*384 + 256 + o];
    const float a   = 1.0f / (1.0f + expf(-alpha[0]));
    const size_t li = ((size_t)b*OO + o)*NS + s;
    float lf = lfA[li];
    if (flag[b*NS + s]) lf = 0.5f*(lf + lfB[li]);
    const float go  = gout[li];
    const float v   = lf*(1.0f - a) + go*a + idv;
    outp[NP_ELEMS + li] = fmaxf(v, 0.0f);
}

extern "C" void kernel_launch(void* const* d_in, const int* in_sizes, int n_in,
                              void* d_out, int out_size, void* d_ws, size_t ws_size,
                              hipStream_t stream)
{
    const float* p        = (const float*)d_in[0];
    const float* f        = (const float*)d_in[1];
    const float* w_convs  = (const float*)d_in[2];
    const float* s_convs  = (const float*)d_in[3];
    const float* b_convs  = (const float*)d_in[4];
    const float* w_attn_l = (const float*)d_in[5];
    const float* s_attn_l = (const float*)d_in[6];
    const float* b_attn_l = (const float*)d_in[7];
    const float* w_gconvs = (const float*)d_in[8];
    const float* s_gconvs = (const float*)d_in[9];
    const float* b_gconvs = (const float*)d_in[10];
    const float* w_attn_g = (const float*)d_in[11];
    const float* s_attn_g = (const float*)d_in[12];
    const float* b_attn_g = (const float*)d_in[13];
    const float* w_skip   = (const float*)d_in[14];
    const float* b_skip   = (const float*)d_in[15];
    const float* z        = (const float*)d_in[16];
    const float* alpha    = (const float*)d_in[17];

    float* out = (float*)d_out;
    float* ws  = (float*)d_ws;
    float* lfA   = ws + WS_LFA;
    float* lfB   = ws + WS_LFB;
    float* gout  = ws + WS_GO;
    float* H     = ws + WS_H;
    float* fi    = ws + WS_FI;
    int*   idx   = (int*)(ws + WS_IDX);
    int*   gidxA = (int*)(ws + WS_GIDXA);
    int*   gidxB = (int*)(ws + WS_GIDXB);
    int*   flag  = (int*)(ws + WS_FLAG);
    float* probs = ws + WS_PROBS;
    float* gp    = ws + WS_GP;
    float* gf    = ws + WS_GF;
    float* newp  = out;

    hipLaunchKernelGGL(k_fps,       dim3(BB),         dim3(1024), 0, stream, p, idx, newp);
    hipLaunchKernelGGL(k_gather_fi, dim3(BB*64),      dim3(256),  0, stream, f, idx, fi);
    hipLaunchKernelGGL(k_ball2,     dim3(NS/4, BB),   dim3(256),  0, stream, p, newp, gidxA, gidxB, flag);
    hipLaunchKernelGGL(k_local,     dim3(NS, BB),     dim3(256),  0, stream, p, f, newp, fi, gidxA, flag, 0,
                       w_convs, s_convs, b_convs, w_attn_l, s_attn_l, b_attn_l, lfA);
    hipLaunchKernelGGL(k_local,     dim3(NS, BB),     dim3(256),  0, stream, p, f, newp, fi, gidxB, flag, 1,
                       w_convs, s_convs, b_convs, w_attn_l, s_attn_l, b_attn_l, lfB);
    hipLaunchKernelGGL(k_H,         dim3(NS/32, BB),  dim3(384),  0, stream, newp, fi,
                       w_convs, s_convs, w_gconvs, s_gconvs, w_skip, b_skip, H);
    hipLaunchKernelGGL(k_gattn1,    dim3(MM, BB),     dim3(256),  0, stream, fi, z, newp, probs, gp);
    hipLaunchKernelGGL(k_gattn2,    dim3(MM, BB),     dim3(256),  0, stream, fi, newp, probs, gp, gf);
    hipLaunchKernelGGL(k_gout,      dim3(NS, BB),     dim3(256),  0, stream, gp, gf, newp, fi,
                       w_gconvs, s_gconvs, b_gconvs, w_attn_g, s_attn_g, b_attn_g, gout);
    hipLaunchKernelGGL(k_final,     dim3(NS/2, BB),   dim3(256),  0, stream, lfA, lfB, flag, gout, H, alpha, out);
}

// Round 12
// 1483.212 us; speedup vs baseline: 1.9753x; 1.6763x over previous
//
#include <hip/hip_runtime.h>
#include <hip/hip_bf16.h>
#include <math.h>

#define BB 8
#define NN 4096
#define NS 1024
#define CC 64
#define OO 128
#define MM 16
#define GAMMA_C 16.0f
#define INV_TAU 1.0f
#define KK 32
#define NP_ELEMS (BB*NS*3)

// ---- workspace layout (units: 4-byte elements) ----
#define WS_G     0                           // float[B*N*256]
#define WS_H     (WS_G + BB*NN*256)          // float[B*NS*384]
#define WS_FI    (WS_H + BB*NS*384)          // float[B*C*NS]
#define WS_IDX   (WS_FI + BB*CC*NS)          // int[B*NS]
#define WS_GIDXA (WS_IDX + BB*NS)            // int[B*NS*K]
#define WS_GIDXB (WS_GIDXA + BB*NS*KK)       // int[B*NS*K]
#define WS_FLAG  (WS_GIDXB + BB*NS*KK)       // int[B*NS]
#define WS_PROBS (WS_FLAG + BB*NS)           // float[B*M*NS]
#define WS_GP    (WS_PROBS + BB*MM*NS)       // float[B*M*3]
#define WS_GF    (WS_GP + BB*MM*3)           // float[B*C*M]
#define WS_CG    (WS_GF + BB*CC*MM)          // float[B*O]

__device__ inline float wave_max_f(float v) {
#pragma unroll
    for (int o = 32; o; o >>= 1) v = fmaxf(v, __shfl_xor(v, o, 64));
    return v;
}
__device__ inline float wave_sum_f(float v) {
#pragma unroll
    for (int o = 32; o; o >>= 1) v += __shfl_xor(v, o, 64);
    return v;
}

// DPP-based packed (distbits, ~idx) max step. Positive f32 order == uint
// order; lo = ~idx tie-breaks to the SMALLEST index (numpy argmax
// first-occurrence). bound_ctrl=1: unwritten lanes read 0 = losing candidate.
template<int CTRL>
__device__ inline void dpp_max_step(unsigned& hi, unsigned& lo) {
    const unsigned nh = (unsigned)__builtin_amdgcn_mov_dpp((int)hi, CTRL, 0xF, 0xF, true);
    const unsigned nl = (unsigned)__builtin_amdgcn_mov_dpp((int)lo, CTRL, 0xF, 0xF, true);
    if (nh > hi || (nh == hi && nl > lo)) { hi = nh; lo = nl; }
}
#define ROR1  0x121
#define ROR2  0x122
#define ROR4  0x124
#define ROR8  0x128
#define BC15  0x142
#define BC31  0x143

// ---------------- 1. Farthest point sampling (frozen from R11) ----------------
__global__ __launch_bounds__(1024) void k_fps(const float* __restrict__ p,
                                              int* __restrict__ idx_out,
                                              float* __restrict__ newp)
{
#pragma clang fp contract(off)
    const int b    = blockIdx.x;
    const int tid  = threadIdx.x;
    const int lane = tid & 63;
    const int wave = tid >> 6;     // 0..15
    __shared__ float px[NN], py[NN], pz[NN];
    __shared__ unsigned phi[2][16], plo[2][16];
    __shared__ int sidx[NS];
    const float* pb = p + (size_t)b*NN*3;
    float pxr[4], pyr[4], pzr[4], dd[4];
#pragma unroll
    for (int q = 0; q < 4; ++q) {
        const int j = tid + q*1024;
        const float x = pb[j*3+0], y = pb[j*3+1], z = pb[j*3+2];
        px[j] = x; py[j] = y; pz[j] = z;
        pxr[q] = x; pyr[q] = y; pzr[q] = z;
        dd[q] = 1e10f;
    }
    if (tid == 0) sidx[0] = 0;
    __syncthreads();
    int last = 0;
    for (int it = 1; it < NS; ++it) {
        const float lx = px[last], ly = py[last], lz = pz[last];
        unsigned bh = 0u, bl = 0u;
#pragma unroll
        for (int q = 0; q < 4; ++q) {
            const float dx = pxr[q]-lx, dy = pyr[q]-ly, dz = pzr[q]-lz;
            const float d = dx*dx + dy*dy + dz*dz;
            dd[q] = fminf(dd[q], d);
            const unsigned ch = __float_as_uint(dd[q]);
            const unsigned cl = ~(unsigned)(tid + q*1024);
            if (ch > bh || (ch == bh && cl > bl)) { bh = ch; bl = cl; }
        }
        dpp_max_step<ROR1>(bh, bl);
        dpp_max_step<ROR2>(bh, bl);
        dpp_max_step<ROR4>(bh, bl);
        dpp_max_step<ROR8>(bh, bl);
        dpp_max_step<BC15>(bh, bl);
        dpp_max_step<BC31>(bh, bl);   // lane 63 holds the wave max
        const int buf = it & 1;
        if (lane == 63) { phi[buf][wave] = bh; plo[buf][wave] = bl; }
        __syncthreads();
        unsigned h2 = phi[buf][lane & 15], l2 = plo[buf][lane & 15];
        dpp_max_step<ROR1>(h2, l2);
        dpp_max_step<ROR2>(h2, l2);
        dpp_max_step<ROR4>(h2, l2);
        dpp_max_step<ROR8>(h2, l2);
        last = (int)(~l2);
        if (tid == 0) sidx[it] = last;
    }
    __syncthreads();
    for (int s = tid; s < NS; s += 1024) {
        const int j = sidx[s];
        idx_out[b*NS + s] = j;
        newp[((size_t)b*NS + s)*3 + 0] = px[j];
        newp[((size_t)b*NS + s)*3 + 1] = py[j];
        newp[((size_t)b*NS + s)*3 + 2] = pz[j];
    }
}

// ---------------- 2. gather fi ----------------
__global__ __launch_bounds__(256) void k_gather_fi(const float* __restrict__ f,
                                                   const int* __restrict__ idx,
                                                   float* __restrict__ fi)
{
    const int bc = blockIdx.x;
    const int b  = bc >> 6;
    const float* frow = f + (size_t)bc * NN;
    float* firow = fi + (size_t)bc * NS;
    const int* ib = idx + b*NS;
    for (int s = threadIdx.x; s < NS; s += 256) firow[s] = frow[ib[s]];
}

// ---------------- 3. ball query with marginal-pair dual sets ----------------
__global__ __launch_bounds__(256) void k_ball2(const float* __restrict__ p,
                                               const float* __restrict__ newp,
                                               int* __restrict__ gA, int* __restrict__ gB,
                                               int* __restrict__ flag)
{
    const int b    = blockIdx.y;
    const int wave = threadIdx.x >> 6;
    const int lane = threadIdx.x & 63;
    const int s    = blockIdx.x * 4 + wave;
    __shared__ int sA[4][KK], sB[4][KK];
    const float* pb = p + (size_t)b*NN*3;
    const double sx = (double)newp[((size_t)b*NS+s)*3+0];
    const double sy = (double)newp[((size_t)b*NS+s)*3+1];
    const double sz = (double)newp[((size_t)b*NS+s)*3+2];
    const double ns2 = sx*sx + sy*sy + sz*sz;
    const double R2D = (double)(0.0225f);
    const double EPSD = 1.5e-7;
    int cntA = 0, cntB = 0, firstA = 0, firstB = 0;
    for (int base = 0; base < NN; base += 64) {
        const int j = base + lane;
        const double x = (double)pb[j*3+0];
        const double y = (double)pb[j*3+1];
        const double z = (double)pb[j*3+2];
        const double d2 = (ns2 + (x*x + y*y + z*z)) - 2.0*(x*sx + y*sy + z*sz);
        const bool inA = (d2 <= R2D + EPSD);
        const bool inB = (d2 <= R2D - EPSD);
        const unsigned long long mA = __ballot(inA);
        const unsigned long long mB = __ballot(inB);
        const unsigned long long below = (1ull << lane) - 1ull;
        if (cntA == 0 && mA) firstA = base + __builtin_ctzll(mA);
        if (cntB == 0 && mB) firstB = base + __builtin_ctzll(mB);
        if (inA) { const int pos = cntA + __popcll(mA & below); if (pos < KK) sA[wave][pos] = j; }
        if (inB) { const int pos = cntB + __popcll(mB & below); if (pos < KK) sB[wave][pos] = j; }
        cntA += __popcll(mA);
        cntB += __popcll(mB);
        if (cntB >= KK) break;
    }
    for (int q = cntA + lane; q < KK; q += 64) sA[wave][q] = firstA;
    for (int q = cntB + lane; q < KK; q += 64) sB[wave][q] = firstB;
    __syncthreads();
    const unsigned long long dm = __ballot(lane < KK && (sA[wave][lane] != sB[wave][lane]));
    int* outA = gA + ((size_t)b*NS + s)*KK;
    int* outB = gB + ((size_t)b*NS + s)*KK;
    if (lane < KK) { outA[lane] = sA[wave][lane]; outB[lane] = sB[wave][lane]; }
    if (lane == 0) flag[b*NS + s] = (dm != 0ull) ? 1 : 0;
}

// ---------------- 4. G[b,j,0:256] over all N points (restructured local) ----------------
// G[o,j] = scale_o*(Wp_o.p_j + (W2_o+W3_o).f_j) + bias_o  (o<128: x/conv ; o>=128: a/attn_l)
// Verified output-equivalent to the literal local branch (R5 ablation).
__global__ __launch_bounds__(256) void k_G(const float* __restrict__ p, const float* __restrict__ f,
    const float* __restrict__ w_convs, const float* __restrict__ s_convs, const float* __restrict__ b_convs,
    const float* __restrict__ w_attn_l, const float* __restrict__ s_attn_l, const float* __restrict__ b_attn_l,
    float* __restrict__ G)
{
    const int b  = blockIdx.y;
    const int j0 = blockIdx.x * 32;
    const int tid = threadIdx.x;       // = o in [0,256)
    __shared__ float sf[64][32];
    __shared__ float sp[3][32];
    for (int i = tid; i < 64*32; i += 256) {
        const int c = i >> 5, t = i & 31;
        sf[c][t] = f[((size_t)b*64 + c)*NN + j0 + t];
    }
    if (tid < 96) {
        const int d = tid / 32, t = tid % 32;
        sp[d][t] = p[((size_t)b*NN + j0 + t)*3 + d];
    }
    __syncthreads();
    const float* wrow; float scale, bias;
    if (tid < 128) { wrow = w_convs + tid*131;        scale = s_convs[tid];        bias = b_convs[tid]; }
    else           { wrow = w_attn_l + (tid-128)*131; scale = s_attn_l[tid-128];   bias = b_attn_l[tid-128]; }
    const float wp0 = wrow[0], wp1 = wrow[1], wp2 = wrow[2];
    float wc[64];
#pragma unroll
    for (int c = 0; c < 64; ++c) wc[c] = wrow[3+c] + wrow[67+c];
    float* Gout = G + ((size_t)b*NN + j0)*256 + tid;
#pragma unroll 1
    for (int t4 = 0; t4 < 8; ++t4) {
        const int t = t4*4;
        float a0 = wp0*sp[0][t+0] + wp1*sp[1][t+0] + wp2*sp[2][t+0];
        float a1 = wp0*sp[0][t+1] + wp1*sp[1][t+1] + wp2*sp[2][t+1];
        float a2 = wp0*sp[0][t+2] + wp1*sp[1][t+2] + wp2*sp[2][t+2];
        float a3 = wp0*sp[0][t+3] + wp1*sp[1][t+3] + wp2*sp[2][t+3];
#pragma unroll
        for (int c = 0; c < 64; ++c) {
            const float4 v = *reinterpret_cast<const float4*>(&sf[c][t]);
            a0 += wc[c]*v.x; a1 += wc[c]*v.y; a2 += wc[c]*v.z; a3 += wc[c]*v.w;
        }
        Gout[(size_t)(t+0)*256] = scale*a0 + bias;
        Gout[(size_t)(t+1)*256] = scale*a1 + bias;
        Gout[(size_t)(t+2)*256] = scale*a2 + bias;
        Gout[(size_t)(t+3)*256] = scale*a3 + bias;
    }
}

// ---------------- 5. H[b,s,0:384] ----------------
// sec0: Hx = s_convs*(Wp.np + W3.fi) ; sec1: Bx = s_gconvs*(Wp_g.np + W3_g.fi)
// sec2: identity = w_skip.fi + b_skip.  (R6 ablation: output-equivalent.)
__global__ __launch_bounds__(384) void k_H(const float* __restrict__ newp, const float* __restrict__ fi,
    const float* __restrict__ w_convs, const float* __restrict__ s_convs,
    const float* __restrict__ w_gconvs, const float* __restrict__ s_gconvs,
    const float* __restrict__ w_skip, const float* __restrict__ b_skip,
    float* __restrict__ H)
{
    const int b  = blockIdx.y;
    const int s0 = blockIdx.x * 32;
    const int tid = threadIdx.x;   // 384
    __shared__ float sfi[64][32];
    __shared__ float snp[3][32];
    for (int i = tid; i < 64*32; i += 384) {
        const int c = i >> 5, t = i & 31;
        sfi[c][t] = fi[((size_t)b*64 + c)*NS + s0 + t];
    }
    for (int i = tid; i < 96; i += 384) {
        const int d = i / 32, t = i % 32;
        snp[d][t] = newp[((size_t)b*NS + s0 + t)*3 + d];
    }
    __syncthreads();
    const int sec = tid >> 7, oo = tid & 127;
    float wp0 = 0.f, wp1 = 0.f, wp2 = 0.f, scale = 1.0f, bias = 0.0f;
    float wc[64];
    if (sec == 0) {
        const float* w = w_convs + oo*131;
        wp0 = w[0]; wp1 = w[1]; wp2 = w[2];
#pragma unroll
        for (int c = 0; c < 64; ++c) wc[c] = w[67+c];
        scale = s_convs[oo];
    } else if (sec == 1) {
        const float* w = w_gconvs + oo*131;
        wp0 = w[0]; wp1 = w[1]; wp2 = w[2];
#pragma unroll
        for (int c = 0; c < 64; ++c) wc[c] = w[67+c];
        scale = s_gconvs[oo];
    } else {
        const float* w = w_skip + oo*64;
#pragma unroll
        for (int c = 0; c < 64; ++c) wc[c] = w[c];
        bias = b_skip[oo];
    }
    float* Hout = H + ((size_t)b*NS + s0)*384 + tid;
#pragma unroll 1
    for (int t4 = 0; t4 < 8; ++t4) {
        const int t = t4*4;
        float a0 = wp0*snp[0][t+0] + wp1*snp[1][t+0] + wp2*snp[2][t+0];
        float a1 = wp0*snp[0][t+1] + wp1*snp[1][t+1] + wp2*snp[2][t+1];
        float a2 = wp0*snp[0][t+2] + wp1*snp[1][t+2] + wp2*snp[2][t+2];
        float a3 = wp0*snp[0][t+3] + wp1*snp[1][t+3] + wp2*snp[2][t+3];
#pragma unroll
        for (int c = 0; c < 64; ++c) {
            const float4 v = *reinterpret_cast<const float4*>(&sfi[c][t]);
            a0 += wc[c]*v.x; a1 += wc[c]*v.y; a2 += wc[c]*v.z; a3 += wc[c]*v.w;
        }
        Hout[(size_t)(t+0)*384] = scale*a0 + bias;
        Hout[(size_t)(t+1)*384] = scale*a1 + bias;
        Hout[(size_t)(t+2)*384] = scale*a2 + bias;
        Hout[(size_t)(t+3)*384] = scale*a3 + bias;
    }
}

// ---------------- 6a. imap softmax over n + global_p ----------------
__global__ __launch_bounds__(256) void k_gattn1(const float* __restrict__ fi, const float* __restrict__ z,
    const float* __restrict__ newp, float* __restrict__ probs, float* __restrict__ gp)
{
    const int m = blockIdx.x, b = blockIdx.y;
    const int tid = threadIdx.x;
    __shared__ float zr[64];
    __shared__ float r0[4], r1[4], r2[4], r3[4];
    __shared__ float bcast[2];
    if (tid < 64) zr[tid] = z[m*64 + tid];
    __syncthreads();
    float v0=0,v1=0,v2=0,v3=0;
    for (int c = 0; c < 64; ++c) {
        const float zc = zr[c];
        const float* fr = fi + ((size_t)b*64 + c)*NS;
        v0 += zc * fr[tid];
        v1 += zc * fr[tid + 256];
        v2 += zc * fr[tid + 512];
        v3 += zc * fr[tid + 768];
    }
    float mx = fmaxf(fmaxf(v0,v1), fmaxf(v2,v3));
    mx = wave_max_f(mx);
    if ((tid&63)==0) r0[tid>>6] = mx;
    __syncthreads();
    if (tid == 0) bcast[0] = fmaxf(fmaxf(r0[0],r0[1]), fmaxf(r0[2],r0[3]));
    __syncthreads();
    mx = bcast[0];
    const float e0 = expf(v0-mx), e1 = expf(v1-mx), e2 = expf(v2-mx), e3 = expf(v3-mx);
    float sum = wave_sum_f(e0+e1+e2+e3);
    if ((tid&63)==0) r0[tid>>6] = sum;
    __syncthreads();
    if (tid == 0) bcast[1] = r0[0]+r0[1]+r0[2]+r0[3];
    __syncthreads();
    const float denom = bcast[1];
    float px=0, py=0, pz=0;
    const float ee[4] = {e0,e1,e2,e3};
#pragma unroll
    for (int q = 0; q < 4; ++q) {
        const int n = tid + q*256;
        const float pn = ee[q] / denom;
        probs[((size_t)b*MM + m)*NS + n] = pn;
        px += pn * newp[((size_t)b*NS+n)*3+0];
        py += pn * newp[((size_t)b*NS+n)*3+1];
        pz += pn * newp[((size_t)b*NS+n)*3+2];
    }
    px = wave_sum_f(px); py = wave_sum_f(py); pz = wave_sum_f(pz);
    if ((tid&63)==0) { r1[tid>>6]=px; r2[tid>>6]=py; r3[tid>>6]=pz; }
    __syncthreads();
    if (tid == 0) {
        gp[((size_t)b*MM+m)*3+0] = r1[0]+r1[1]+r1[2]+r1[3];
        gp[((size_t)b*MM+m)*3+1] = r2[0]+r2[1]+r2[2]+r2[3];
        gp[((size_t)b*MM+m)*3+2] = r3[0]+r3[1]+r3[2]+r3[3];
    }
}

// ---------------- 6b. gaussian kernel attn + global_f ----------------
__global__ __launch_bounds__(256) void k_gattn2(const float* __restrict__ fi, const float* __restrict__ newp,
    const float* __restrict__ probs, const float* __restrict__ gp, float* __restrict__ gf)
{
    const int m = blockIdx.x, b = blockIdx.y;
    const int tid = threadIdx.x;
    __shared__ float at[NS];
    __shared__ float part[64][4];
    const float gx = gp[((size_t)b*MM+m)*3+0];
    const float gy = gp[((size_t)b*MM+m)*3+1];
    const float gz = gp[((size_t)b*MM+m)*3+2];
    const float g2 = gx*gx + gy*gy + gz*gz;
#pragma unroll
    for (int q = 0; q < 4; ++q) {
        const int n = tid + q*256;
        const float nx = newp[((size_t)b*NS+n)*3+0];
        const float ny = newp[((size_t)b*NS+n)*3+1];
        const float nz = newp[((size_t)b*NS+n)*3+2];
        const float n2 = nx*nx + ny*ny + nz*nz;
        float dot = gx*nx; dot += gy*ny; dot += gz*nz;
        const float d2 = fmaxf((g2 + n2) - 2.0f*dot, 0.0f);
        at[n] = probs[((size_t)b*MM+m)*NS+n] * expf(-GAMMA_C*d2);
    }
    __syncthreads();
    const int d = tid >> 2, q = tid & 3;
    const float* fr = fi + ((size_t)b*64 + d)*NS + q*256;
    const float* ar = at + q*256;
    float acc = 0.f;
    for (int i = 0; i < 256; i += 4) {
        const float4 fv = *reinterpret_cast<const float4*>(fr + i);
        acc += fv.x*ar[i] + fv.y*ar[i+1] + fv.z*ar[i+2] + fv.w*ar[i+3];
    }
    part[d][q] = acc;
    __syncthreads();
    if (tid < 64) gf[((size_t)b*64 + tid)*MM + m] = part[tid][0]+part[tid][1]+part[tid][2]+part[tid][3];
}

// ---------------- 6c. global A-side table + softmax over m -> cg[b,o] ----------------
// (R6 ablation: output-equivalent to literal global branch.)
__global__ __launch_bounds__(128) void k_gattn3(const float* __restrict__ gp, const float* __restrict__ gf,
    const float* __restrict__ w_gconvs, const float* __restrict__ s_gconvs, const float* __restrict__ b_gconvs,
    const float* __restrict__ w_attn_g, const float* __restrict__ s_attn_g, const float* __restrict__ b_attn_g,
    float* __restrict__ cg)
{
    const int b = blockIdx.x;
    const int o = threadIdx.x;
    const float* wx = w_gconvs + o*131;
    const float* wa = w_attn_g + o*131;
    const float sx = s_gconvs[o], bx = b_gconvs[o];
    const float sa = s_attn_g[o], ba = b_attn_g[o];
    float Ax[MM], Aa[MM];
    for (int m = 0; m < MM; ++m) {
        const float g0 = gp[((size_t)b*MM+m)*3+0];
        const float g1 = gp[((size_t)b*MM+m)*3+1];
        const float g2 = gp[((size_t)b*MM+m)*3+2];
        float accx = wx[0]*g0 + wx[1]*g1 + wx[2]*g2;
        float acca = wa[0]*g0 + wa[1]*g1 + wa[2]*g2;
        for (int c = 0; c < 64; ++c) {
            const float gv = gf[((size_t)b*64+c)*MM + m];
            accx += (wx[3+c] + wx[67+c]) * gv;
            acca += (wa[3+c] + wa[67+c]) * gv;
        }
        Ax[m] = sx*accx + bx;
        Aa[m] = (sa*acca + ba) * INV_TAU;
    }
    float mx = Aa[0];
#pragma unroll
    for (int m = 1; m < MM; ++m) mx = fmaxf(mx, Aa[m]);
    float den = 0.f, num = 0.f;
#pragma unroll
    for (int m = 0; m < MM; ++m) { const float e = expf(Aa[m]-mx); den += e; num += e*Ax[m]; }
    cg[b*OO + o] = num / den;
}

// ---------------- 7. final: dual gather-softmax from G + combine ----------------
__global__ __launch_bounds__(256) void k_final(const float* __restrict__ G, const float* __restrict__ H,
    const float* __restrict__ cg, const int* __restrict__ gidxA, const int* __restrict__ gidxB,
    const int* __restrict__ flag, const float* __restrict__ alpha,
    float* __restrict__ outp)
{
    const int b  = blockIdx.y;
    const int s0 = blockIdx.x * 2;
    const int tid = threadIdx.x;
    const int o = tid & 127, si = tid >> 7;
    const int s = s0 + si;
    __shared__ int jgA[2][32], jgB[2][32];
    if (tid < 64)                 jgA[tid>>5][tid&31] = gidxA[((size_t)b*NS + s0 + (tid>>5))*KK + (tid&31)];
    else if (tid < 128)           { const int t2 = tid-64; jgB[t2>>5][t2&31] = gidxB[((size_t)b*NS + s0 + (t2>>5))*KK + (t2&31)]; }
    __syncthreads();
    const float* Hrow = H + ((size_t)b*NS + s)*384;
    const float Hx  = Hrow[o];
    const float Bx  = Hrow[128+o];
    const float idv = Hrow[256+o];
    const float co  = cg[b*OO + o];
    const float a   = 1.0f / (1.0f + expf(-alpha[0]));
    const float* Gb = G + (size_t)b*NN*256 + o;
    float gav[KK], gxv[KK];
#pragma unroll
    for (int k = 0; k < KK; ++k) {
        const float* g2 = Gb + (size_t)jgA[si][k]*256;
        gxv[k] = g2[0];
        gav[k] = g2[128] * INV_TAU;
    }
    float mx = gav[0];
#pragma unroll
    for (int k = 1; k < KK; ++k) mx = fmaxf(mx, gav[k]);
    float den = 0.f, num = 0.f;
#pragma unroll
    for (int k = 0; k < KK; ++k) { const float e = expf(gav[k]-mx); den += e; num += e*gxv[k]; }
    float lf = num/den - Hx;
    if (flag[b*NS + s]) {   // wave-uniform (si fixed per wave)
#pragma unroll
        for (int k = 0; k < KK; ++k) {
            const float* g2 = Gb + (size_t)jgB[si][k]*256;
            gxv[k] = g2[0];
            gav[k] = g2[128] * INV_TAU;
        }
        float mxB = gav[0];
#pragma unroll
        for (int k = 1; k < KK; ++k) mxB = fmaxf(mxB, gav[k]);
        float denB = 0.f, numB = 0.f;
#pragma unroll
        for (int k = 0; k < KK; ++k) { const float e = expf(gav[k]-mxB); denB += e; numB += e*gxv[k]; }
        lf = 0.5f*(lf + (numB/denB - Hx));
    }
    const float go = co - Bx;
    const float v  = lf*(1.0f - a) + go*a + idv;
    outp[NP_ELEMS + ((size_t)b*OO + o)*NS + s] = fmaxf(v, 0.0f);
}

extern "C" void kernel_launch(void* const* d_in, const int* in_sizes, int n_in,
                              void* d_out, int out_size, void* d_ws, size_t ws_size,
                              hipStream_t stream)
{
    const float* p        = (const float*)d_in[0];
    const float* f        = (const float*)d_in[1];
    const float* w_convs  = (const float*)d_in[2];
    const float* s_convs  = (const float*)d_in[3];
    const float* b_convs  = (const float*)d_in[4];
    const float* w_attn_l = (const float*)d_in[5];
    const float* s_attn_l = (const float*)d_in[6];
    const float* b_attn_l = (const float*)d_in[7];
    const float* w_gconvs = (const float*)d_in[8];
    const float* s_gconvs = (const float*)d_in[9];
    const float* b_gconvs = (const float*)d_in[10];
    const float* w_attn_g = (const float*)d_in[11];
    const float* s_attn_g = (const float*)d_in[12];
    const float* b_attn_g = (const float*)d_in[13];
    const float* w_skip   = (const float*)d_in[14];
    const float* b_skip   = (const float*)d_in[15];
    const float* z        = (const float*)d_in[16];
    const float* alpha    = (const float*)d_in[17];

    float* out = (float*)d_out;
    float* ws  = (float*)d_ws;
    float* G     = ws + WS_G;
    float* H     = ws + WS_H;
    float* fi    = ws + WS_FI;
    int*   idx   = (int*)(ws + WS_IDX);
    int*   gidxA = (int*)(ws + WS_GIDXA);
    int*   gidxB = (int*)(ws + WS_GIDXB);
    int*   flag  = (int*)(ws + WS_FLAG);
    float* probs = ws + WS_PROBS;
    float* gp    = ws + WS_GP;
    float* gf    = ws + WS_GF;
    float* cg    = ws + WS_CG;
    float* newp  = out;

    hipLaunchKernelGGL(k_fps,       dim3(BB),         dim3(1024), 0, stream, p, idx, newp);
    hipLaunchKernelGGL(k_gather_fi, dim3(BB*64),      dim3(256),  0, stream, f, idx, fi);
    hipLaunchKernelGGL(k_ball2,     dim3(NS/4, BB),   dim3(256),  0, stream, p, newp, gidxA, gidxB, flag);
    hipLaunchKernelGGL(k_G,         dim3(NN/32, BB),  dim3(256),  0, stream, p, f,
                       w_convs, s_convs, b_convs, w_attn_l, s_attn_l, b_attn_l, G);
    hipLaunchKernelGGL(k_H,         dim3(NS/32, BB),  dim3(384),  0, stream, newp, fi,
                       w_convs, s_convs, w_gconvs, s_gconvs, w_skip, b_skip, H);
    hipLaunchKernelGGL(k_gattn1,    dim3(MM, BB),     dim3(256),  0, stream, fi, z, newp, probs, gp);
    hipLaunchKernelGGL(k_gattn2,    dim3(MM, BB),     dim3(256),  0, stream, fi, newp, probs, gp, gf);
    hipLaunchKernelGGL(k_gattn3,    dim3(BB),         dim3(128),  0, stream, gp, gf,
                       w_gconvs, s_gconvs, b_gconvs, w_attn_g, s_attn_g, b_attn_g, cg);
    hipLaunchKernelGGL(k_final,     dim3(NS/2, BB),   dim3(256),  0, stream, G, H, cg, gidxA, gidxB, flag, alpha, out);
}